// Round 13
// baseline (170.614 us; speedup 1.0000x reference)
//
#include <hip/hip_runtime.h>

typedef __attribute__((ext_vector_type(8))) short bf16x8;
typedef __attribute__((ext_vector_type(4))) float f32x4;
typedef __attribute__((ext_vector_type(4))) unsigned short us4;

#define DEV __device__ __forceinline__

static constexpr int Bn = 2, Tn = 4096, Dn = 1024, Pn = 16, Hn = 64;
static constexpr int BT = Bn * Tn;      // 8192
static constexpr int NC = 3 * Dn;       // 3072 packed basis columns
static constexpr int NUNIT = 544;       // KV-split units per batch (chunk=256 keys)

// workspace offsets (bytes)
static constexpr size_t OFF_ROUTING = 0;                                  // 8192*16*4
static constexpr size_t OFF_XBF     = OFF_ROUTING + (size_t)BT * 16 * 4;  // 8192*1024*2
static constexpr size_t OFF_BPK     = OFF_XBF + (size_t)BT * Dn * 2;      // 3072*1024*2
static constexpr size_t OFF_QKV     = OFF_BPK + (size_t)NC * Dn * 2;      // 8192*192*4
static constexpr size_t OFF_QBF     = OFF_QKV + (size_t)BT * 192 * 4;     // 8192*64*2
static constexpr size_t OFF_KBF     = OFF_QBF + (size_t)BT * 64 * 2;
static constexpr size_t OFF_VT      = OFF_KBF + (size_t)BT * 64 * 2;      // [B][64][4096]
static constexpr size_t OFF_ATTNB   = OFF_VT + (size_t)BT * 64 * 2;
static constexpr size_t OFF_OWEFF   = OFF_ATTNB + (size_t)BT * 64 * 2;    // 1024*64*2
// attention partials ALIAS dead regions:
//   po: 2*544 units * 64q * 64h * f32 = 17.8 MB -> at OFF_XBF (xbf 16 MB + bpk 6 MB both dead
//       after proj_gemm; po ends at 18.35 MB < OFF_QKV)
//   ml: 2*544 * 128 * f32 = 557 KB -> at OFF_QKV (qkv dead after rope)

DEV unsigned short f2bf(float f) {
  unsigned int u = __builtin_bit_cast(unsigned int, f);
  u += 0x7fffu + ((u >> 16) & 1u);
  return (unsigned short)(u >> 16);
}

DEV unsigned int cvtpk(float a, float b) {
  unsigned int r;
  asm("v_cvt_pk_bf16_f32 %0, %1, %2" : "=v"(r) : "v"(a), "v"(b));
  return r;
}

DEV void gll16(const void* g, void* l) {
  __builtin_amdgcn_global_load_lds(
      (const __attribute__((address_space(1))) void*)g,
      (__attribute__((address_space(3))) void*)l, 16, 0, 0);
}

// ---------------- prep: router (blocks 0..1023) + pack_bases (1024..1791) + pack_ow (1792..2047)
__global__ __launch_bounds__(256)
void prep_kernel(const float* __restrict__ x, const float* __restrict__ w,
                 const float* __restrict__ kproto, const float* __restrict__ vproto,
                 const float* __restrict__ qb, const float* __restrict__ kb,
                 const float* __restrict__ vb, const float* __restrict__ ow,
                 float* __restrict__ routing, unsigned short* __restrict__ xbf,
                 unsigned short* __restrict__ bpk, unsigned short* __restrict__ oweff)
{
  __shared__ float lgs[8][16];
  __shared__ float tile[64][65];
  const int bid = blockIdx.x;
  const int tid = threadIdx.x;

  if (bid < 1024) {
    // ---------- router: rmsnorm -> proto logits -> softmax^2 -> routing; also x->bf16 ----------
    const int wid = tid >> 6, lane = tid & 63;
    const int t0 = bid * 8;

    float wv[16];
#pragma unroll
    for (int c = 0; c < 4; ++c) {
      float4 f = *(const float4*)(w + c * 256 + lane * 4);
      wv[c*4+0] = f.x; wv[c*4+1] = f.y; wv[c*4+2] = f.z; wv[c*4+3] = f.w;
    }

    float xr[2][16];
    float rs[2];
#pragma unroll
    for (int rr = 0; rr < 2; ++rr) {
      const int row = t0 + wid * 2 + rr;
      float ss = 0.f;
#pragma unroll
      for (int c = 0; c < 4; ++c) {
        float4 f = *(const float4*)(x + (size_t)row * 1024 + c * 256 + lane * 4);
        xr[rr][c*4+0] = f.x; xr[rr][c*4+1] = f.y; xr[rr][c*4+2] = f.z; xr[rr][c*4+3] = f.w;
        ss += f.x*f.x + f.y*f.y + f.z*f.z + f.w*f.w;
        us4 o; o[0] = f2bf(f.x); o[1] = f2bf(f.y); o[2] = f2bf(f.z); o[3] = f2bf(f.w);
        *(us4*)(xbf + (size_t)row * 1024 + c * 256 + lane * 4) = o;
      }
#pragma unroll
      for (int off = 1; off < 64; off <<= 1) ss += __shfl_xor(ss, off, 64);
      rs[rr] = rsqrtf(ss * (1.f / 1024.f) + 1e-6f);
    }

    for (int p = 0; p < 16; ++p) {
      float d0 = 0.f, d1 = 0.f;
#pragma unroll
      for (int c = 0; c < 4; ++c) {
        float4 f = *(const float4*)(kproto + (size_t)p * 1024 + c * 256 + lane * 4);
        float k0 = f.x * wv[c*4+0], k1 = f.y * wv[c*4+1], k2 = f.z * wv[c*4+2], k3 = f.w * wv[c*4+3];
        d0 += xr[0][c*4+0]*k0 + xr[0][c*4+1]*k1 + xr[0][c*4+2]*k2 + xr[0][c*4+3]*k3;
        d1 += xr[1][c*4+0]*k0 + xr[1][c*4+1]*k1 + xr[1][c*4+2]*k2 + xr[1][c*4+3]*k3;
      }
#pragma unroll
      for (int off = 1; off < 64; off <<= 1) {
        d0 += __shfl_xor(d0, off, 64);
        d1 += __shfl_xor(d1, off, 64);
      }
      if (lane == 0) {
        lgs[wid*2+0][p] = d0 * rs[0] * 0.03125f;   // /sqrt(1024)
        lgs[wid*2+1][p] = d1 * rs[1] * 0.03125f;
      }
    }
    __syncthreads();
    if (tid < 8) {
      float lg[16];
#pragma unroll
      for (int p = 0; p < 16; ++p) lg[p] = lgs[tid][p];
      float m = -1e30f;
#pragma unroll
      for (int p = 0; p < 16; ++p) m = fmaxf(m, lg[p]);
      float aw[16]; float s = 0.f;
#pragma unroll
      for (int p = 0; p < 16; ++p) { aw[p] = __expf(lg[p] - m); s += aw[p]; }
      float inv = 1.f / s;
      float rt[16];
#pragma unroll
      for (int q = 0; q < 16; ++q) {
        float a = 0.f;
#pragma unroll
        for (int p = 0; p < 16; ++p) a += aw[p] * vproto[p * 16 + q];
        rt[q] = a * inv;  // GAIN = 1.0
      }
      float m2 = -1e30f;
#pragma unroll
      for (int q = 0; q < 16; ++q) m2 = fmaxf(m2, rt[q]);
      float e[16]; float s2 = 0.f;
#pragma unroll
      for (int q = 0; q < 16; ++q) { e[q] = __expf(rt[q] - m2); s2 += e[q]; }
      float inv2 = 1.f / s2;
#pragma unroll
      for (int q = 0; q < 16; ++q) routing[(size_t)(t0 + tid) * 16 + q] = e[q] * inv2;
    }
  } else if (bid < 1792) {
    // ---------- pack bases: [p][d][h] f32 -> Bpack[c][d] bf16, c = basis*1024 + h*16 + p -------
    const int pbid = bid - 1024;          // 768 = 3 * 16 * 16
    const int bs = pbid >> 8;
    const int p = (pbid >> 4) & 15;
    const int dt = pbid & 15;
    const float* src = bs == 0 ? qb : (bs == 1 ? kb : vb);
#pragma unroll
    for (int j = 0; j < 4; ++j) {
      int slot = tid + j * 256;
      int r = slot >> 4;          // d-local 0..63
      int c4 = slot & 15;         // h group
      float4 v = *(const float4*)(src + (size_t)p * 65536 + (size_t)(dt * 64 + r) * 64 + c4 * 4);
      tile[r][c4*4+0] = v.x; tile[r][c4*4+1] = v.y; tile[r][c4*4+2] = v.z; tile[r][c4*4+3] = v.w;
    }
    __syncthreads();
#pragma unroll
    for (int j = 0; j < 4; ++j) {
      int slot = tid + j * 256;
      int h = slot >> 4;          // 0..63
      int d4 = slot & 15;
      us4 o;
      o[0] = f2bf(tile[d4*4+0][h]); o[1] = f2bf(tile[d4*4+1][h]);
      o[2] = f2bf(tile[d4*4+2][h]); o[3] = f2bf(tile[d4*4+3][h]);
      int c = bs * 1024 + h * 16 + p;
      *(us4*)(bpk + (size_t)c * 1024 + dt * 64 + d4 * 4) = o;
    }
  } else {
    // ---------- pack o_w: ow_eff[o][h] = sum_n o_w[o][n*64+h] (bf16) ----------
    int idx = (bid - 1792) * 256 + tid;   // 65536
    int o = idx >> 6, h = idx & 63;
    float s = 0.f;
#pragma unroll
    for (int n = 0; n < 16; ++n) s += ow[(size_t)o * 1024 + n * 64 + h];
    oweff[idx] = f2bf(s);
  }
}

// ---------------- projection GEMM (transposed): D[c, t] = sum_d Bpack[c,d] x[t,d] ----------
// ONE-barrier 3-buffer pipeline (T3 issue-early order + T4 counted vmcnt + T5 setprio):
//   per K-step: vmcnt(4) [tile kt's loads, all older retired] -> s_barrier ->
//   STAGE(kt+2 -> buf[(kt+2)%3]) -> ds_read(buf[kt%3]) -> lgkmcnt(0) ->
//   setprio(1) MFMA setprio(0).
// Race audit: RAW on buf[kt%3]: every wave's vmcnt precedes the barrier -> all waves'
//   tile-kt loads landed.  WAR on buf[(kt+2)%3]: its readers (iter kt-1) issued
//   lgkmcnt(0) before reaching the iter-kt barrier -> reads retired.
// 512 threads (8 waves, 2c x 4t), 128x128 tile, BK=64, T2 swizzle (0 conflicts).
// LDS 3 x 32KB = 96KB -> 1 block/CU, 8 waves; role diversity replaces cross-block overlap.
__global__ __launch_bounds__(512)
void proj_gemm_kernel(const unsigned short* __restrict__ bpk,
                      const unsigned short* __restrict__ xbf,
                      const float* __restrict__ routing,
                      float* __restrict__ qkv)
{
  __shared__ __attribute__((aligned(16))) unsigned short As[3][128][64];  // c-rows (Bpack)
  __shared__ __attribute__((aligned(16))) unsigned short Bs[3][128][64];  // t-rows (x)
  const int bid = blockIdx.x;                 // 1536 = 24 c-tiles x 64 t-tiles
  const int swz = (bid & 7) * 192 + (bid >> 3);
  const int tt = swz / 24, ct = swz - tt * 24;
  const int c0 = ct << 7, t0 = tt << 7;
  const int tid = threadIdx.x, wid = tid >> 6, lane = tid & 63;
  const int wm = (wid >> 2) << 6;             // c-offset: 0 / 64
  const int wn = (wid & 3) << 5;              // t-offset: 0 / 32 / 64 / 96
  const int l15 = lane & 15, l4 = lane >> 4;
  const int sx = (l15 & 7) << 3;              // read-side XOR (elements)

  f32x4 acc[4][2];
#pragma unroll
  for (int m = 0; m < 4; ++m)
#pragma unroll
    for (int n = 0; n < 2; ++n) acc[m][n] = (f32x4){0.f, 0.f, 0.f, 0.f};

  // stage one K-step: A 128x64 + B 128x64 in 2 rounds of 64 rows each (4 gll16/thread).
  // source row = i*64 + (tid>>3) (row&7 == lane>>3); source col = inverse-swizzled granule;
  // LDS dest = linear, wave base row i*64 + wid*8 (HW adds lane*16 -> 8 rows/wave).
#define PROJ_STAGE(kt, pb) do {                                               \
    const int k0_ = (kt) * 64;                                                \
    const int r_ = tid >> 3;                                                  \
    const int cc_ = 8 * ((lane & 7) ^ (lane >> 3));  /* inverse-swz source */ \
    gll16(bpk + (size_t)(c0 + r_) * 1024 + k0_ + cc_,      &As[pb][wid * 8][0]);      \
    gll16(bpk + (size_t)(c0 + 64 + r_) * 1024 + k0_ + cc_, &As[pb][64 + wid * 8][0]); \
    gll16(xbf + (size_t)(t0 + r_) * 1024 + k0_ + cc_,      &Bs[pb][wid * 8][0]);      \
    gll16(xbf + (size_t)(t0 + 64 + r_) * 1024 + k0_ + cc_, &Bs[pb][64 + wid * 8][0]); \
  } while (0)

  PROJ_STAGE(0, 0);
  PROJ_STAGE(1, 1);

  int cb = 0;
  for (int kt = 0; kt < 16; ++kt) {
    // wait only the CURRENT tile's 4 loads (oldest); the next tile's stay in flight
    if (kt < 15) asm volatile("s_waitcnt vmcnt(4)" ::: "memory");
    else         asm volatile("s_waitcnt vmcnt(0)" ::: "memory");
    asm volatile("s_barrier" ::: "memory");
    // stage kt+2 into the buffer whose readers (iter kt-1) retired before this barrier
    if (kt < 14) {
      const int pb = (cb == 0) ? 2 : cb - 1;   // (kt+2)%3
      PROJ_STAGE(kt + 2, pb);
    }
#pragma unroll
    for (int kk = 0; kk < 2; ++kk) {
      bf16x8 af[4], bfr[2];
#pragma unroll
      for (int m = 0; m < 4; ++m)
        af[m] = *(const bf16x8*)&As[cb][wm + m * 16 + l15][(kk * 32 + l4 * 8) ^ sx];
#pragma unroll
      for (int n = 0; n < 2; ++n)
        bfr[n] = *(const bf16x8*)&Bs[cb][wn + n * 16 + l15][(kk * 32 + l4 * 8) ^ sx];
      asm volatile("s_waitcnt lgkmcnt(0)" ::: "memory");
      __builtin_amdgcn_s_setprio(1);
#pragma unroll
      for (int m = 0; m < 4; ++m)
#pragma unroll
        for (int n = 0; n < 2; ++n)
          acc[m][n] = __builtin_amdgcn_mfma_f32_16x16x32_bf16(af[m], bfr[n], acc[m][n], 0, 0, 0);
      __builtin_amdgcn_s_setprio(0);
    }
    cb = (cb == 2) ? 0 : cb + 1;
  }
#undef PROJ_STAGE

  // epilogue: s = sum_p routing[t,p] * S[p,t]; p = l4*4+j within fragment rows
#pragma unroll
  for (int n = 0; n < 2; ++n) {
    const int t = t0 + wn + n * 16 + l15;
    const float4 rt = *(const float4*)(routing + (size_t)t * 16 + l4 * 4);
#pragma unroll
    for (int m = 0; m < 4; ++m) {
      float s = acc[m][n][0] * rt.x + acc[m][n][1] * rt.y
              + acc[m][n][2] * rt.z + acc[m][n][3] * rt.w;
      s += __shfl_xor(s, 16, 64);
      s += __shfl_xor(s, 32, 64);
      if (l4 == 0) {
        const int h16 = (c0 + wm + m * 16) >> 4;   // basis*64 + h
        qkv[(size_t)t * 192 + h16] = s;
      }
    }
  }
}

// ---------------- RoPE + convert to bf16 (+V transpose) ----------
// q is scaled by 1/sqrt(H) * log2(e) so attention scores live in exp2 domain.
__global__ __launch_bounds__(256)
void rope_kernel(const float* __restrict__ qkv, const float* __restrict__ cosb,
                 const float* __restrict__ sinb, unsigned short* __restrict__ qbf,
                 unsigned short* __restrict__ kbf, unsigned short* __restrict__ vT)
{
  constexpr float QS = 0.125f * 1.4426950408889634f;
  __shared__ float vs[64][33];
  const int tid = threadIdx.x;
  const int bt0 = blockIdx.x * 32;
  const int tokl = tid >> 3;
  const int h0 = (tid & 7) * 4;
  const size_t bt = bt0 + tokl;
  const float* base = qkv + bt * 192;
  float4 q1 = *(const float4*)(base + h0);
  float4 q2 = *(const float4*)(base + h0 + 32);
  float4 k1 = *(const float4*)(base + 64 + h0);
  float4 k2 = *(const float4*)(base + 64 + h0 + 32);
  float4 v1 = *(const float4*)(base + 128 + h0);
  float4 v2 = *(const float4*)(base + 128 + h0 + 32);
  const float* cp = cosb + bt * 64;
  const float* sp = sinb + bt * 64;
  float4 c1 = *(const float4*)(cp + h0), c2 = *(const float4*)(cp + h0 + 32);
  float4 s1 = *(const float4*)(sp + h0), s2 = *(const float4*)(sp + h0 + 32);

  us4 uq1, uq2, uk1, uk2;
  uq1[0] = f2bf((q1.x * c1.x - q2.x * s1.x) * QS);
  uq1[1] = f2bf((q1.y * c1.y - q2.y * s1.y) * QS);
  uq1[2] = f2bf((q1.z * c1.z - q2.z * s1.z) * QS);
  uq1[3] = f2bf((q1.w * c1.w - q2.w * s1.w) * QS);
  uq2[0] = f2bf((q2.x * c2.x + q1.x * s2.x) * QS);
  uq2[1] = f2bf((q2.y * c2.y + q1.y * s2.y) * QS);
  uq2[2] = f2bf((q2.z * c2.z + q1.z * s2.z) * QS);
  uq2[3] = f2bf((q2.w * c2.w + q1.w * s2.w) * QS);
  uk1[0] = f2bf(k1.x * c1.x - k2.x * s1.x);
  uk1[1] = f2bf(k1.y * c1.y - k2.y * s1.y);
  uk1[2] = f2bf(k1.z * c1.z - k2.z * s1.z);
  uk1[3] = f2bf(k1.w * c1.w - k2.w * s1.w);
  uk2[0] = f2bf(k2.x * c2.x + k1.x * s2.x);
  uk2[1] = f2bf(k2.y * c2.y + k1.y * s2.y);
  uk2[2] = f2bf(k2.z * c2.z + k1.z * s2.z);
  uk2[3] = f2bf(k2.w * c2.w + k1.w * s2.w);
  *(us4*)(qbf + bt * 64 + h0) = uq1;
  *(us4*)(qbf + bt * 64 + h0 + 32) = uq2;
  *(us4*)(kbf + bt * 64 + h0) = uk1;
  *(us4*)(kbf + bt * 64 + h0 + 32) = uk2;

  vs[h0 + 0][tokl] = v1.x; vs[h0 + 1][tokl] = v1.y; vs[h0 + 2][tokl] = v1.z; vs[h0 + 3][tokl] = v1.w;
  vs[h0 + 32][tokl] = v2.x; vs[h0 + 33][tokl] = v2.y; vs[h0 + 34][tokl] = v2.z; vs[h0 + 35][tokl] = v2.w;
  __syncthreads();
  const int h = tid >> 2, c8 = (tid & 3) * 8;
  const int b = bt0 >> 12, tb0 = bt0 & 4095;
  us4 o0, o1;
  o0[0] = f2bf(vs[h][c8 + 0]); o0[1] = f2bf(vs[h][c8 + 1]);
  o0[2] = f2bf(vs[h][c8 + 2]); o0[3] = f2bf(vs[h][c8 + 3]);
  o1[0] = f2bf(vs[h][c8 + 4]); o1[1] = f2bf(vs[h][c8 + 5]);
  o1[2] = f2bf(vs[h][c8 + 6]); o1[3] = f2bf(vs[h][c8 + 7]);
  unsigned short* vp = vT + ((size_t)b * 64 + h) * 4096 + tb0 + c8;
  *(us4*)vp = o0;
  *(us4*)(vp + 4) = o1;
}

// ---------------- flash attention partials: KV-split (chunk=256), no LDS, no barriers ------
// unit u in [0,544): group g = qt>>2 (S(g) = 2g(g+1)), qt = 4g + r0/(g+1), chunk c = r0%(g+1).
// Swapped QK^T with PERMUTED key rows: mfma-row r of block j holds physical key
//   key0 + 32*(j>>1) + 4*(j&1) + 8*(r>>2) + (r&3)
// so the C-fragment's per-lane keys (8*l4 + 0..3 per j-pair) are 8-consecutive, and the
// lane's own cvt_pk words concatenate into a 16x16x32 PV B-fragment (no lane exchange).
__global__ __launch_bounds__(256)
void attn_kernel(const unsigned short* __restrict__ qbf,
                 const unsigned short* __restrict__ kbf,
                 const unsigned short* __restrict__ vT,
                 float* __restrict__ po, float* __restrict__ ml)
{
  const int bid = blockIdx.x;
  const int b = bid / NUNIT, u = bid - b * NUNIT;
  int g = 0;
  while (u >= 2 * (g + 1) * (g + 2)) ++g;      // S(g) = 2g(g+1)
  const int r0 = u - 2 * g * (g + 1);
  const int qq = r0 / (g + 1);
  const int qt = 4 * g + qq;
  const int c = r0 - qq * (g + 1);
  const int ks = c * 256;
  const int ke = min(ks + 256, (qt + 1) * 64);

  const int tid = threadIdx.x, w = tid >> 6, lane = tid & 63;
  const int l15 = lane & 15, l4 = lane >> 4;
  const int q0w = qt * 64 + w * 16;
  const int qg = q0w + l15;

  const unsigned short* qp = qbf + (size_t)(b * 4096 + qg) * 64 + l4 * 8;
  bf16x8 qf0 = *(const bf16x8*)qp;
  bf16x8 qf1 = *(const bf16x8*)(qp + 32);

  f32x4 oacc[4];
#pragma unroll
  for (int hf = 0; hf < 4; ++hf) oacc[hf] = (f32x4){0.f, 0.f, 0.f, 0.f};
  float m = -1e30f, l = 0.f;

  const int kew = min(ke, q0w + 16);           // per-wave causal early exit
  const int nst = (kew - ks + 63) >> 6;
  const int kperm = 8 * (l15 >> 2) + (l15 & 3);  // permuted A-row -> key offset

  for (int st = 0; st < nst; ++st) {
    const int key0 = ks + st * 64;
    // ---- QK^T (swapped: A=K permuted rows, B=Q cols) ----
    f32x4 s[4];
#pragma unroll
    for (int j = 0; j < 4; ++j) {
      const int krow = key0 + 32 * (j >> 1) + 4 * (j & 1) + kperm;
      const unsigned short* kp = kbf + (size_t)(b * 4096 + krow) * 64 + l4 * 8;
      bf16x8 ka = *(const bf16x8*)kp;
      bf16x8 kc = *(const bf16x8*)(kp + 32);
      f32x4 z = (f32x4){0.f, 0.f, 0.f, 0.f};
      z = __builtin_amdgcn_mfma_f32_16x16x32_bf16(ka, qf0, z, 0, 0, 0);
      s[j] = __builtin_amdgcn_mfma_f32_16x16x32_bf16(kc, qf1, z, 0, 0, 0);
    }
    // ---- V fragments: A-frag rows=h(l15), k = 8 consecutive keys (16B aligned) ----
    bf16x8 vf[4][2];
#pragma unroll
    for (int J = 0; J < 2; ++J)
#pragma unroll
      for (int hf = 0; hf < 4; ++hf)
        vf[hf][J] = *(const bf16x8*)(vT + ((size_t)(b * 64 + hf * 16 + l15)) * 4096
                                     + key0 + J * 32 + l4 * 8);
    // ---- causal mask (permuted key mapping) ----
    if (key0 + 63 > q0w) {
#pragma unroll
      for (int j = 0; j < 4; ++j) {
        const int kb0 = key0 + 32 * (j >> 1) + 4 * (j & 1) + 8 * l4;
#pragma unroll
        for (int rr = 0; rr < 4; ++rr)
          if (kb0 + rr > qg) s[j][rr] = -1e30f;
      }
    }
    // ---- online softmax (per-lane q col; reduce over l4 groups) ----
    float pmax = -1e30f;
#pragma unroll
    for (int j = 0; j < 4; ++j)
#pragma unroll
      for (int rr = 0; rr < 4; ++rr) pmax = fmaxf(pmax, s[j][rr]);
    pmax = fmaxf(pmax, __shfl_xor(pmax, 16, 64));
    pmax = fmaxf(pmax, __shfl_xor(pmax, 32, 64));
    const float mn = fmaxf(m, pmax);
    const float sc = __builtin_amdgcn_exp2f(m - mn);
    m = mn;
    l *= sc;
#pragma unroll
    for (int hf = 0; hf < 4; ++hf) {
      oacc[hf][0] *= sc; oacc[hf][1] *= sc; oacc[hf][2] *= sc; oacc[hf][3] *= sc;
    }
    float rs = 0.f;
    unsigned int cvw[4][2];
#pragma unroll
    for (int j = 0; j < 4; ++j) {
      const float e0 = (s[j][0] > -1e29f) ? __builtin_amdgcn_exp2f(s[j][0] - m) : 0.f;
      const float e1 = (s[j][1] > -1e29f) ? __builtin_amdgcn_exp2f(s[j][1] - m) : 0.f;
      const float e2 = (s[j][2] > -1e29f) ? __builtin_amdgcn_exp2f(s[j][2] - m) : 0.f;
      const float e3 = (s[j][3] > -1e29f) ? __builtin_amdgcn_exp2f(s[j][3] - m) : 0.f;
      rs += (e0 + e1) + (e2 + e3);
      cvw[j][0] = cvtpk(e0, e1);
      cvw[j][1] = cvtpk(e2, e3);
    }
    rs += __shfl_xor(rs, 16, 64);
    rs += __shfl_xor(rs, 32, 64);
    l += rs;
    // ---- PV: A=V^T (h x 32keys), B=P^T from the lane's own cvt_pk words ----
#pragma unroll
    for (int J = 0; J < 2; ++J) {
      union { unsigned int uu[4]; bf16x8 v; } pk;
      pk.uu[0] = cvw[2 * J][0];
      pk.uu[1] = cvw[2 * J][1];
      pk.uu[2] = cvw[2 * J + 1][0];
      pk.uu[3] = cvw[2 * J + 1][1];
#pragma unroll
      for (int hf = 0; hf < 4; ++hf)
        oacc[hf] = __builtin_amdgcn_mfma_f32_16x16x32_bf16(vf[hf][J], pk.v, oacc[hf], 0, 0, 0);
    }
  }

  // ---- write partials: po[u][q][h], ml[u][{m,l}][q] ----
  const size_t ug = (size_t)b * NUNIT + u;
  float* pop = po + (ug * 64 + w * 16 + l15) * 64;
#pragma unroll
  for (int hf = 0; hf < 4; ++hf)
    *(f32x4*)(pop + hf * 16 + l4 * 4) = oacc[hf];
  if (l4 == 0) {
    ml[ug * 128 + w * 16 + l15] = m;
    ml[ug * 128 + 64 + w * 16 + l15] = l;
  }
}

// ---------------- combine KV-split partials -> attnb (bf16) ----------
__global__ __launch_bounds__(256)
void combine_kernel(const float* __restrict__ po, const float* __restrict__ ml,
                    unsigned short* __restrict__ attnb)
{
  const int bid = blockIdx.x;          // 128 = B * 64 qtiles
  const int b = bid >> 6, qt = bid & 63;
  const int g = qt >> 2, r = qt & 3;
  const int nch = g + 1;
  const size_t ub = (size_t)b * NUNIT + (size_t)2 * g * (g + 1) + (size_t)r * (g + 1);
  const int tid = threadIdx.x;
  const int q = tid >> 2, hc = (tid & 3) * 16;

  float mt = -1e30f;
  for (int i = 0; i < nch; ++i) mt = fmaxf(mt, ml[(ub + i) * 128 + q]);
  float lt = 0.f;
  float4 a0 = {0,0,0,0}, a1 = {0,0,0,0}, a2 = {0,0,0,0}, a3 = {0,0,0,0};
  for (int i = 0; i < nch; ++i) {
    const float mi = ml[(ub + i) * 128 + q];
    const float wi = (mi > -1e29f) ? __builtin_amdgcn_exp2f(mi - mt) : 0.f;
    lt += wi * ml[(ub + i) * 128 + 64 + q];
    const float* pp = po + ((ub + i) * 64 + q) * 64 + hc;
    float4 f0 = *(const float4*)(pp + 0);
    float4 f1 = *(const float4*)(pp + 4);
    float4 f2 = *(const float4*)(pp + 8);
    float4 f3 = *(const float4*)(pp + 12);
    a0.x += wi * f0.x; a0.y += wi * f0.y; a0.z += wi * f0.z; a0.w += wi * f0.w;
    a1.x += wi * f1.x; a1.y += wi * f1.y; a1.z += wi * f1.z; a1.w += wi * f1.w;
    a2.x += wi * f2.x; a2.y += wi * f2.y; a2.z += wi * f2.z; a2.w += wi * f2.w;
    a3.x += wi * f3.x; a3.y += wi * f3.y; a3.z += wi * f3.z; a3.w += wi * f3.w;
  }
  const float inv = (lt > 0.f) ? 1.f / lt : 0.f;
  unsigned short* op = attnb + ((size_t)b * 4096 + qt * 64 + q) * 64 + hc;
  us4 o;
  o[0] = f2bf(a0.x * inv); o[1] = f2bf(a0.y * inv); o[2] = f2bf(a0.z * inv); o[3] = f2bf(a0.w * inv);
  *(us4*)(op + 0) = o;
  o[0] = f2bf(a1.x * inv); o[1] = f2bf(a1.y * inv); o[2] = f2bf(a1.z * inv); o[3] = f2bf(a1.w * inv);
  *(us4*)(op + 4) = o;
  o[0] = f2bf(a2.x * inv); o[1] = f2bf(a2.y * inv); o[2] = f2bf(a2.z * inv); o[3] = f2bf(a2.w * inv);
  *(us4*)(op + 8) = o;
  o[0] = f2bf(a3.x * inv); o[1] = f2bf(a3.y * inv); o[2] = f2bf(a3.z * inv); o[3] = f2bf(a3.w * inv);
  *(us4*)(op + 12) = o;
}

// ---------------- o_proj GEMM: out[bt][o] = attn[bt][:] . ow_eff[o][:] ----------
__global__ __launch_bounds__(256)
void oproj_kernel(const unsigned short* __restrict__ attnb,
                  const unsigned short* __restrict__ oweff,
                  float* __restrict__ out)
{
  __shared__ __attribute__((aligned(16))) unsigned short As[128][64];
  __shared__ __attribute__((aligned(16))) unsigned short Bs[128][64];
  const int bid = blockIdx.x;   // 512 = 64 x 8
  const int swz = (bid & 7) * 64 + (bid >> 3);
  const int mt = swz >> 3, nt = swz & 7;
  const int m0 = mt << 7, n0 = nt << 7;
  const int tid = threadIdx.x, wid = tid >> 6, lane = tid & 63;
  const int wm = (wid >> 1) << 6, wn = (wid & 1) << 6;
  const int l15 = lane & 15, l4 = lane >> 4;

#pragma unroll
  for (int i = 0; i < 4; ++i) {
    int ch = wid * 4 + i;
    int r = ch * 8 + (lane >> 3), c = (lane & 7) * 8;
    gll16(attnb + (size_t)(m0 + r) * 64 + c, &As[ch * 8][0]);
    gll16(oweff + (size_t)(n0 + r) * 64 + c, &Bs[ch * 8][0]);
  }
  __syncthreads();

  f32x4 acc[4][4];
#pragma unroll
  for (int m = 0; m < 4; ++m)
#pragma unroll
    for (int n = 0; n < 4; ++n) acc[m][n] = (f32x4){0.f, 0.f, 0.f, 0.f};
#pragma unroll
  for (int kk = 0; kk < 2; ++kk) {
    bf16x8 af[4], bfr[4];
#pragma unroll
    for (int m = 0; m < 4; ++m) af[m] = *(const bf16x8*)&As[wm + m * 16 + l15][kk * 32 + l4 * 8];
#pragma unroll
    for (int n = 0; n < 4; ++n) bfr[n] = *(const bf16x8*)&Bs[wn + n * 16 + l15][kk * 32 + l4 * 8];
#pragma unroll
    for (int m = 0; m < 4; ++m)
#pragma unroll
      for (int n = 0; n < 4; ++n)
        acc[m][n] = __builtin_amdgcn_mfma_f32_16x16x32_bf16(af[m], bfr[n], acc[m][n], 0, 0, 0);
  }
#pragma unroll
  for (int m = 0; m < 4; ++m)
#pragma unroll
    for (int n = 0; n < 4; ++n)
#pragma unroll
      for (int r = 0; r < 4; ++r)
        out[(size_t)(m0 + wm + m * 16 + l4 * 4 + r) * 1024 + n0 + wn + n * 16 + l15] = acc[m][n][r];
}

extern "C" void kernel_launch(void* const* d_in, const int* in_sizes, int n_in,
                              void* d_out, int out_size, void* d_ws, size_t ws_size,
                              hipStream_t stream) {
  const float* x      = (const float*)d_in[0];
  const float* cosb   = (const float*)d_in[1];
  const float* sinb   = (const float*)d_in[2];
  const float* qw     = (const float*)d_in[3];
  const float* kproto = (const float*)d_in[4];
  const float* vproto = (const float*)d_in[5];
  const float* qb     = (const float*)d_in[6];
  const float* kb     = (const float*)d_in[7];
  const float* vb     = (const float*)d_in[8];
  const float* ow     = (const float*)d_in[9];
  float* out = (float*)d_out;
  char* ws = (char*)d_ws;

  float* routing        = (float*)(ws + OFF_ROUTING);
  unsigned short* xbf   = (unsigned short*)(ws + OFF_XBF);
  unsigned short* bpk   = (unsigned short*)(ws + OFF_BPK);
  float* qkv            = (float*)(ws + OFF_QKV);
  unsigned short* qbf   = (unsigned short*)(ws + OFF_QBF);
  unsigned short* kbf   = (unsigned short*)(ws + OFF_KBF);
  unsigned short* vT    = (unsigned short*)(ws + OFF_VT);
  unsigned short* attnb = (unsigned short*)(ws + OFF_ATTNB);
  unsigned short* oweff = (unsigned short*)(ws + OFF_OWEFF);
  // attention partials alias dead regions: po over xbf+bpk (dead after proj),
  // ml over qkv (dead after rope)
  float* po             = (float*)(ws + OFF_XBF);
  float* ml             = (float*)(ws + OFF_QKV);

  prep_kernel<<<2048, 256, 0, stream>>>(x, qw, kproto, vproto, qb, kb, vb, ow,
                                        routing, xbf, bpk, oweff);
  proj_gemm_kernel<<<1536, 512, 0, stream>>>(bpk, xbf, routing, qkv);
  rope_kernel<<<BT / 32, 256, 0, stream>>>(qkv, cosb, sinb, qbf, kbf, vT);
  attn_kernel<<<Bn * NUNIT, 256, 0, stream>>>(qbf, kbf, vT, po, ml);
  combine_kernel<<<128, 256, 0, stream>>>(po, ml, attnb);
  oproj_kernel<<<512, 256, 0, stream>>>(attnb, oweff, out);
}

// Round 14
// 143.303 us; speedup vs baseline: 1.1906x; 1.1906x over previous
//
#include <hip/hip_runtime.h>

typedef __attribute__((ext_vector_type(8))) short bf16x8;
typedef __attribute__((ext_vector_type(4))) float f32x4;
typedef __attribute__((ext_vector_type(4))) unsigned short us4;

#define DEV __device__ __forceinline__

static constexpr int Bn = 2, Tn = 4096, Dn = 1024, Pn = 16, Hn = 64;
static constexpr int BT = Bn * Tn;      // 8192
static constexpr int NC = 3 * Dn;       // 3072 packed basis columns
static constexpr int NUNIT = 544;       // KV-split units per batch (chunk=256 keys)

// workspace offsets (bytes)
static constexpr size_t OFF_ROUTING = 0;                                  // 8192*16*4
static constexpr size_t OFF_XBF     = OFF_ROUTING + (size_t)BT * 16 * 4;  // 8192*1024*2
static constexpr size_t OFF_BPK     = OFF_XBF + (size_t)BT * Dn * 2;      // 3072*1024*2
static constexpr size_t OFF_QKV     = OFF_BPK + (size_t)NC * Dn * 2;      // 8192*192*4
static constexpr size_t OFF_QBF     = OFF_QKV + (size_t)BT * 192 * 4;     // 8192*64*2
static constexpr size_t OFF_KBF     = OFF_QBF + (size_t)BT * 64 * 2;
static constexpr size_t OFF_VT      = OFF_KBF + (size_t)BT * 64 * 2;      // [B][64][4096]
static constexpr size_t OFF_ATTNB   = OFF_VT + (size_t)BT * 64 * 2;
static constexpr size_t OFF_OWEFF   = OFF_ATTNB + (size_t)BT * 64 * 2;    // 1024*64*2
// attention partials ALIAS dead regions:
//   po: 2*544 units * 64q * 64h * f32 = 17.8 MB -> at OFF_XBF (xbf 16 MB + bpk 6 MB both dead
//       after proj_gemm; po ends at 18.35 MB < OFF_QKV)
//   ml: 2*544 * 128 * f32 = 557 KB -> at OFF_QKV (qkv dead after rope)

DEV unsigned short f2bf(float f) {
  unsigned int u = __builtin_bit_cast(unsigned int, f);
  u += 0x7fffu + ((u >> 16) & 1u);
  return (unsigned short)(u >> 16);
}

DEV unsigned int cvtpk(float a, float b) {
  unsigned int r;
  asm("v_cvt_pk_bf16_f32 %0, %1, %2" : "=v"(r) : "v"(a), "v"(b));
  return r;
}

DEV void gll16(const void* g, void* l) {
  __builtin_amdgcn_global_load_lds(
      (const __attribute__((address_space(1))) void*)g,
      (__attribute__((address_space(3))) void*)l, 16, 0, 0);
}

// ---------------- prep: router (blocks 0..1023) + pack_bases (1024..1791) + pack_ow (1792..2047)
__global__ __launch_bounds__(256)
void prep_kernel(const float* __restrict__ x, const float* __restrict__ w,
                 const float* __restrict__ kproto, const float* __restrict__ vproto,
                 const float* __restrict__ qb, const float* __restrict__ kb,
                 const float* __restrict__ vb, const float* __restrict__ ow,
                 float* __restrict__ routing, unsigned short* __restrict__ xbf,
                 unsigned short* __restrict__ bpk, unsigned short* __restrict__ oweff)
{
  __shared__ float lgs[8][16];
  __shared__ float tile[64][65];
  const int bid = blockIdx.x;
  const int tid = threadIdx.x;

  if (bid < 1024) {
    // ---------- router: rmsnorm -> proto logits -> softmax^2 -> routing; also x->bf16 ----------
    const int wid = tid >> 6, lane = tid & 63;
    const int t0 = bid * 8;

    float wv[16];
#pragma unroll
    for (int c = 0; c < 4; ++c) {
      float4 f = *(const float4*)(w + c * 256 + lane * 4);
      wv[c*4+0] = f.x; wv[c*4+1] = f.y; wv[c*4+2] = f.z; wv[c*4+3] = f.w;
    }

    float xr[2][16];
    float rs[2];
#pragma unroll
    for (int rr = 0; rr < 2; ++rr) {
      const int row = t0 + wid * 2 + rr;
      float ss = 0.f;
#pragma unroll
      for (int c = 0; c < 4; ++c) {
        float4 f = *(const float4*)(x + (size_t)row * 1024 + c * 256 + lane * 4);
        xr[rr][c*4+0] = f.x; xr[rr][c*4+1] = f.y; xr[rr][c*4+2] = f.z; xr[rr][c*4+3] = f.w;
        ss += f.x*f.x + f.y*f.y + f.z*f.z + f.w*f.w;
        us4 o; o[0] = f2bf(f.x); o[1] = f2bf(f.y); o[2] = f2bf(f.z); o[3] = f2bf(f.w);
        *(us4*)(xbf + (size_t)row * 1024 + c * 256 + lane * 4) = o;
      }
#pragma unroll
      for (int off = 1; off < 64; off <<= 1) ss += __shfl_xor(ss, off, 64);
      rs[rr] = rsqrtf(ss * (1.f / 1024.f) + 1e-6f);
    }

    for (int p = 0; p < 16; ++p) {
      float d0 = 0.f, d1 = 0.f;
#pragma unroll
      for (int c = 0; c < 4; ++c) {
        float4 f = *(const float4*)(kproto + (size_t)p * 1024 + c * 256 + lane * 4);
        float k0 = f.x * wv[c*4+0], k1 = f.y * wv[c*4+1], k2 = f.z * wv[c*4+2], k3 = f.w * wv[c*4+3];
        d0 += xr[0][c*4+0]*k0 + xr[0][c*4+1]*k1 + xr[0][c*4+2]*k2 + xr[0][c*4+3]*k3;
        d1 += xr[1][c*4+0]*k0 + xr[1][c*4+1]*k1 + xr[1][c*4+2]*k2 + xr[1][c*4+3]*k3;
      }
#pragma unroll
      for (int off = 1; off < 64; off <<= 1) {
        d0 += __shfl_xor(d0, off, 64);
        d1 += __shfl_xor(d1, off, 64);
      }
      if (lane == 0) {
        lgs[wid*2+0][p] = d0 * rs[0] * 0.03125f;   // /sqrt(1024)
        lgs[wid*2+1][p] = d1 * rs[1] * 0.03125f;
      }
    }
    __syncthreads();
    if (tid < 8) {
      float lg[16];
#pragma unroll
      for (int p = 0; p < 16; ++p) lg[p] = lgs[tid][p];
      float m = -1e30f;
#pragma unroll
      for (int p = 0; p < 16; ++p) m = fmaxf(m, lg[p]);
      float aw[16]; float s = 0.f;
#pragma unroll
      for (int p = 0; p < 16; ++p) { aw[p] = __expf(lg[p] - m); s += aw[p]; }
      float inv = 1.f / s;
      float rt[16];
#pragma unroll
      for (int q = 0; q < 16; ++q) {
        float a = 0.f;
#pragma unroll
        for (int p = 0; p < 16; ++p) a += aw[p] * vproto[p * 16 + q];
        rt[q] = a * inv;  // GAIN = 1.0
      }
      float m2 = -1e30f;
#pragma unroll
      for (int q = 0; q < 16; ++q) m2 = fmaxf(m2, rt[q]);
      float e[16]; float s2 = 0.f;
#pragma unroll
      for (int q = 0; q < 16; ++q) { e[q] = __expf(rt[q] - m2); s2 += e[q]; }
      float inv2 = 1.f / s2;
#pragma unroll
      for (int q = 0; q < 16; ++q) routing[(size_t)(t0 + tid) * 16 + q] = e[q] * inv2;
    }
  } else if (bid < 1792) {
    // ---------- pack bases: [p][d][h] f32 -> Bpack[c][d] bf16, c = basis*1024 + h*16 + p -------
    const int pbid = bid - 1024;          // 768 = 3 * 16 * 16
    const int bs = pbid >> 8;
    const int p = (pbid >> 4) & 15;
    const int dt = pbid & 15;
    const float* src = bs == 0 ? qb : (bs == 1 ? kb : vb);
#pragma unroll
    for (int j = 0; j < 4; ++j) {
      int slot = tid + j * 256;
      int r = slot >> 4;          // d-local 0..63
      int c4 = slot & 15;         // h group
      float4 v = *(const float4*)(src + (size_t)p * 65536 + (size_t)(dt * 64 + r) * 64 + c4 * 4);
      tile[r][c4*4+0] = v.x; tile[r][c4*4+1] = v.y; tile[r][c4*4+2] = v.z; tile[r][c4*4+3] = v.w;
    }
    __syncthreads();
#pragma unroll
    for (int j = 0; j < 4; ++j) {
      int slot = tid + j * 256;
      int h = slot >> 4;          // 0..63
      int d4 = slot & 15;
      us4 o;
      o[0] = f2bf(tile[d4*4+0][h]); o[1] = f2bf(tile[d4*4+1][h]);
      o[2] = f2bf(tile[d4*4+2][h]); o[3] = f2bf(tile[d4*4+3][h]);
      int c = bs * 1024 + h * 16 + p;
      *(us4*)(bpk + (size_t)c * 1024 + dt * 64 + d4 * 4) = o;
    }
  } else {
    // ---------- pack o_w: ow_eff[o][h] = sum_n o_w[o][n*64+h] (bf16) ----------
    int idx = (bid - 1792) * 256 + tid;   // 65536
    int o = idx >> 6, h = idx & 63;
    float s = 0.f;
#pragma unroll
    for (int n = 0; n < 16; ++n) s += ow[(size_t)o * 1024 + n * 64 + h];
    oweff[idx] = f2bf(s);
  }
}

// ---------------- projection GEMM (transposed): D[c, t] = sum_d Bpack[c,d] x[t,d] ----------
// R12-proven config (best measured: 58.5us, MfmaUtil 36.5%, 0 conflicts):
// 512 threads (8 waves, 2c x 4t), 128x128 tile, BK=64, 2 LDS buffers (64 KB -> 2 blocks/CU
// for cross-block drain hiding + L2 panel reuse).  T2 XOR-swizzle; T4 counted vmcnt(4).
__global__ __launch_bounds__(512)
void proj_gemm_kernel(const unsigned short* __restrict__ bpk,
                      const unsigned short* __restrict__ xbf,
                      const float* __restrict__ routing,
                      float* __restrict__ qkv)
{
  __shared__ __attribute__((aligned(16))) unsigned short As[2][128][64];  // c-rows (Bpack)
  __shared__ __attribute__((aligned(16))) unsigned short Bs[2][128][64];  // t-rows (x)
  const int bid = blockIdx.x;                 // 1536 = 24 c-tiles x 64 t-tiles
  const int swz = (bid & 7) * 192 + (bid >> 3);
  const int tt = swz / 24, ct = swz - tt * 24;
  const int c0 = ct << 7, t0 = tt << 7;
  const int tid = threadIdx.x, wid = tid >> 6, lane = tid & 63;
  const int wm = (wid >> 2) << 6;             // c-offset: 0 / 64
  const int wn = (wid & 3) << 5;              // t-offset: 0 / 32 / 64 / 96
  const int l15 = lane & 15, l4 = lane >> 4;
  const int sx = (l15 & 7) << 3;              // read-side XOR (elements)

  f32x4 acc[4][2];
#pragma unroll
  for (int m = 0; m < 4; ++m)
#pragma unroll
    for (int n = 0; n < 2; ++n) acc[m][n] = (f32x4){0.f, 0.f, 0.f, 0.f};

  // stage one K-step: A 128x64 + B 128x64 in 2 rounds of 64 rows each (4 gll16/thread).
  // source row = i*64 + (tid>>3) (row&7 == lane>>3); source col = inverse-swizzled granule;
  // LDS dest = linear, wave base row i*64 + wid*8 (HW adds lane*16 -> 8 rows/wave).
#define PROJ_STAGE(kt, pb) do {                                               \
    const int k0_ = (kt) * 64;                                                \
    const int r_ = tid >> 3;                                                  \
    const int cc_ = 8 * ((lane & 7) ^ (lane >> 3));  /* inverse-swz source */ \
    gll16(bpk + (size_t)(c0 + r_) * 1024 + k0_ + cc_,      &As[pb][wid * 8][0]);      \
    gll16(bpk + (size_t)(c0 + 64 + r_) * 1024 + k0_ + cc_, &As[pb][64 + wid * 8][0]); \
    gll16(xbf + (size_t)(t0 + r_) * 1024 + k0_ + cc_,      &Bs[pb][wid * 8][0]);      \
    gll16(xbf + (size_t)(t0 + 64 + r_) * 1024 + k0_ + cc_, &Bs[pb][64 + wid * 8][0]); \
  } while (0)

  PROJ_STAGE(0, 0);
  PROJ_STAGE(1, 1);

  for (int kt = 0; kt < 16; ++kt) {
    const int cb = kt & 1;
    // wait only for the CURRENT tile's 4 loads; next tile's stay in flight
    if (kt < 15) asm volatile("s_waitcnt vmcnt(4)" ::: "memory");
    else         asm volatile("s_waitcnt vmcnt(0)" ::: "memory");
    asm volatile("s_barrier" ::: "memory");
#pragma unroll
    for (int kk = 0; kk < 2; ++kk) {
      bf16x8 af[4], bfr[2];
#pragma unroll
      for (int m = 0; m < 4; ++m)
        af[m] = *(const bf16x8*)&As[cb][wm + m * 16 + l15][(kk * 32 + l4 * 8) ^ sx];
#pragma unroll
      for (int n = 0; n < 2; ++n)
        bfr[n] = *(const bf16x8*)&Bs[cb][wn + n * 16 + l15][(kk * 32 + l4 * 8) ^ sx];
#pragma unroll
      for (int m = 0; m < 4; ++m)
#pragma unroll
        for (int n = 0; n < 2; ++n)
          acc[m][n] = __builtin_amdgcn_mfma_f32_16x16x32_bf16(af[m], bfr[n], acc[m][n], 0, 0, 0);
    }
    // ds_reads must be retired before other waves may overwrite this buffer
    asm volatile("s_waitcnt lgkmcnt(0)" ::: "memory");
    asm volatile("s_barrier" ::: "memory");
    if (kt < 14) PROJ_STAGE(kt + 2, cb);
  }
#undef PROJ_STAGE

  // epilogue: s = sum_p routing[t,p] * S[p,t]; p = l4*4+j within fragment rows
#pragma unroll
  for (int n = 0; n < 2; ++n) {
    const int t = t0 + wn + n * 16 + l15;
    const float4 rt = *(const float4*)(routing + (size_t)t * 16 + l4 * 4);
#pragma unroll
    for (int m = 0; m < 4; ++m) {
      float s = acc[m][n][0] * rt.x + acc[m][n][1] * rt.y
              + acc[m][n][2] * rt.z + acc[m][n][3] * rt.w;
      s += __shfl_xor(s, 16, 64);
      s += __shfl_xor(s, 32, 64);
      if (l4 == 0) {
        const int h16 = (c0 + wm + m * 16) >> 4;   // basis*64 + h
        qkv[(size_t)t * 192 + h16] = s;
      }
    }
  }
}

// ---------------- RoPE + convert to bf16 (+V transpose) ----------
// q is scaled by 1/sqrt(H) * log2(e) so attention scores live in exp2 domain.
__global__ __launch_bounds__(256)
void rope_kernel(const float* __restrict__ qkv, const float* __restrict__ cosb,
                 const float* __restrict__ sinb, unsigned short* __restrict__ qbf,
                 unsigned short* __restrict__ kbf, unsigned short* __restrict__ vT)
{
  constexpr float QS = 0.125f * 1.4426950408889634f;
  __shared__ float vs[64][33];
  const int tid = threadIdx.x;
  const int bt0 = blockIdx.x * 32;
  const int tokl = tid >> 3;
  const int h0 = (tid & 7) * 4;
  const size_t bt = bt0 + tokl;
  const float* base = qkv + bt * 192;
  float4 q1 = *(const float4*)(base + h0);
  float4 q2 = *(const float4*)(base + h0 + 32);
  float4 k1 = *(const float4*)(base + 64 + h0);
  float4 k2 = *(const float4*)(base + 64 + h0 + 32);
  float4 v1 = *(const float4*)(base + 128 + h0);
  float4 v2 = *(const float4*)(base + 128 + h0 + 32);
  const float* cp = cosb + bt * 64;
  const float* sp = sinb + bt * 64;
  float4 c1 = *(const float4*)(cp + h0), c2 = *(const float4*)(cp + h0 + 32);
  float4 s1 = *(const float4*)(sp + h0), s2 = *(const float4*)(sp + h0 + 32);

  us4 uq1, uq2, uk1, uk2;
  uq1[0] = f2bf((q1.x * c1.x - q2.x * s1.x) * QS);
  uq1[1] = f2bf((q1.y * c1.y - q2.y * s1.y) * QS);
  uq1[2] = f2bf((q1.z * c1.z - q2.z * s1.z) * QS);
  uq1[3] = f2bf((q1.w * c1.w - q2.w * s1.w) * QS);
  uq2[0] = f2bf((q2.x * c2.x + q1.x * s2.x) * QS);
  uq2[1] = f2bf((q2.y * c2.y + q1.y * s2.y) * QS);
  uq2[2] = f2bf((q2.z * c2.z + q1.z * s2.z) * QS);
  uq2[3] = f2bf((q2.w * c2.w + q1.w * s2.w) * QS);
  uk1[0] = f2bf(k1.x * c1.x - k2.x * s1.x);
  uk1[1] = f2bf(k1.y * c1.y - k2.y * s1.y);
  uk1[2] = f2bf(k1.z * c1.z - k2.z * s1.z);
  uk1[3] = f2bf(k1.w * c1.w - k2.w * s1.w);
  uk2[0] = f2bf(k2.x * c2.x + k1.x * s2.x);
  uk2[1] = f2bf(k2.y * c2.y + k1.y * s2.y);
  uk2[2] = f2bf(k2.z * c2.z + k1.z * s2.z);
  uk2[3] = f2bf(k2.w * c2.w + k1.w * s2.w);
  *(us4*)(qbf + bt * 64 + h0) = uq1;
  *(us4*)(qbf + bt * 64 + h0 + 32) = uq2;
  *(us4*)(kbf + bt * 64 + h0) = uk1;
  *(us4*)(kbf + bt * 64 + h0 + 32) = uk2;

  vs[h0 + 0][tokl] = v1.x; vs[h0 + 1][tokl] = v1.y; vs[h0 + 2][tokl] = v1.z; vs[h0 + 3][tokl] = v1.w;
  vs[h0 + 32][tokl] = v2.x; vs[h0 + 33][tokl] = v2.y; vs[h0 + 34][tokl] = v2.z; vs[h0 + 35][tokl] = v2.w;
  __syncthreads();
  const int h = tid >> 2, c8 = (tid & 3) * 8;
  const int b = bt0 >> 12, tb0 = bt0 & 4095;
  us4 o0, o1;
  o0[0] = f2bf(vs[h][c8 + 0]); o0[1] = f2bf(vs[h][c8 + 1]);
  o0[2] = f2bf(vs[h][c8 + 2]); o0[3] = f2bf(vs[h][c8 + 3]);
  o1[0] = f2bf(vs[h][c8 + 4]); o1[1] = f2bf(vs[h][c8 + 5]);
  o1[2] = f2bf(vs[h][c8 + 6]); o1[3] = f2bf(vs[h][c8 + 7]);
  unsigned short* vp = vT + ((size_t)b * 64 + h) * 4096 + tb0 + c8;
  *(us4*)vp = o0;
  *(us4*)(vp + 4) = o1;
}

// ---------------- flash attention partials: KV-split (chunk=256), no LDS, no barriers ------
// unit u in [0,544): group g = qt>>2 (S(g) = 2g(g+1)), qt = 4g + r0/(g+1), chunk c = r0%(g+1).
// Swapped QK^T with PERMUTED key rows: mfma-row r of block j holds physical key
//   key0 + 32*(j>>1) + 4*(j&1) + 8*(r>>2) + (r&3)
// so the C-fragment's per-lane keys (8*l4 + 0..3 per j-pair) are 8-consecutive, and the
// lane's own cvt_pk words concatenate into a 16x16x32 PV B-fragment (no lane exchange).
__global__ __launch_bounds__(256)
void attn_kernel(const unsigned short* __restrict__ qbf,
                 const unsigned short* __restrict__ kbf,
                 const unsigned short* __restrict__ vT,
                 float* __restrict__ po, float* __restrict__ ml)
{
  const int bid = blockIdx.x;
  const int b = bid / NUNIT, u = bid - b * NUNIT;
  int g = 0;
  while (u >= 2 * (g + 1) * (g + 2)) ++g;      // S(g) = 2g(g+1)
  const int r0 = u - 2 * g * (g + 1);
  const int qq = r0 / (g + 1);
  const int qt = 4 * g + qq;
  const int c = r0 - qq * (g + 1);
  const int ks = c * 256;
  const int ke = min(ks + 256, (qt + 1) * 64);

  const int tid = threadIdx.x, w = tid >> 6, lane = tid & 63;
  const int l15 = lane & 15, l4 = lane >> 4;
  const int q0w = qt * 64 + w * 16;
  const int qg = q0w + l15;

  const unsigned short* qp = qbf + (size_t)(b * 4096 + qg) * 64 + l4 * 8;
  bf16x8 qf0 = *(const bf16x8*)qp;
  bf16x8 qf1 = *(const bf16x8*)(qp + 32);

  f32x4 oacc[4];
#pragma unroll
  for (int hf = 0; hf < 4; ++hf) oacc[hf] = (f32x4){0.f, 0.f, 0.f, 0.f};
  float m = -1e30f, l = 0.f;

  const int kew = min(ke, q0w + 16);           // per-wave causal early exit
  const int nst = (kew - ks + 63) >> 6;
  const int kperm = 8 * (l15 >> 2) + (l15 & 3);  // permuted A-row -> key offset

  for (int st = 0; st < nst; ++st) {
    const int key0 = ks + st * 64;
    // ---- QK^T (swapped: A=K permuted rows, B=Q cols) ----
    f32x4 s[4];
#pragma unroll
    for (int j = 0; j < 4; ++j) {
      const int krow = key0 + 32 * (j >> 1) + 4 * (j & 1) + kperm;
      const unsigned short* kp = kbf + (size_t)(b * 4096 + krow) * 64 + l4 * 8;
      bf16x8 ka = *(const bf16x8*)kp;
      bf16x8 kc = *(const bf16x8*)(kp + 32);
      f32x4 z = (f32x4){0.f, 0.f, 0.f, 0.f};
      z = __builtin_amdgcn_mfma_f32_16x16x32_bf16(ka, qf0, z, 0, 0, 0);
      s[j] = __builtin_amdgcn_mfma_f32_16x16x32_bf16(kc, qf1, z, 0, 0, 0);
    }
    // ---- V fragments: A-frag rows=h(l15), k = 8 consecutive keys (16B aligned) ----
    bf16x8 vf[4][2];
#pragma unroll
    for (int J = 0; J < 2; ++J)
#pragma unroll
      for (int hf = 0; hf < 4; ++hf)
        vf[hf][J] = *(const bf16x8*)(vT + ((size_t)(b * 64 + hf * 16 + l15)) * 4096
                                     + key0 + J * 32 + l4 * 8);
    // ---- causal mask (permuted key mapping) ----
    if (key0 + 63 > q0w) {
#pragma unroll
      for (int j = 0; j < 4; ++j) {
        const int kb0 = key0 + 32 * (j >> 1) + 4 * (j & 1) + 8 * l4;
#pragma unroll
        for (int rr = 0; rr < 4; ++rr)
          if (kb0 + rr > qg) s[j][rr] = -1e30f;
      }
    }
    // ---- online softmax (per-lane q col; reduce over l4 groups) ----
    float pmax = -1e30f;
#pragma unroll
    for (int j = 0; j < 4; ++j)
#pragma unroll
      for (int rr = 0; rr < 4; ++rr) pmax = fmaxf(pmax, s[j][rr]);
    pmax = fmaxf(pmax, __shfl_xor(pmax, 16, 64));
    pmax = fmaxf(pmax, __shfl_xor(pmax, 32, 64));
    const float mn = fmaxf(m, pmax);
    const float sc = __builtin_amdgcn_exp2f(m - mn);
    m = mn;
    l *= sc;
#pragma unroll
    for (int hf = 0; hf < 4; ++hf) {
      oacc[hf][0] *= sc; oacc[hf][1] *= sc; oacc[hf][2] *= sc; oacc[hf][3] *= sc;
    }
    float rs = 0.f;
    unsigned int cvw[4][2];
#pragma unroll
    for (int j = 0; j < 4; ++j) {
      const float e0 = (s[j][0] > -1e29f) ? __builtin_amdgcn_exp2f(s[j][0] - m) : 0.f;
      const float e1 = (s[j][1] > -1e29f) ? __builtin_amdgcn_exp2f(s[j][1] - m) : 0.f;
      const float e2 = (s[j][2] > -1e29f) ? __builtin_amdgcn_exp2f(s[j][2] - m) : 0.f;
      const float e3 = (s[j][3] > -1e29f) ? __builtin_amdgcn_exp2f(s[j][3] - m) : 0.f;
      rs += (e0 + e1) + (e2 + e3);
      cvw[j][0] = cvtpk(e0, e1);
      cvw[j][1] = cvtpk(e2, e3);
    }
    rs += __shfl_xor(rs, 16, 64);
    rs += __shfl_xor(rs, 32, 64);
    l += rs;
    // ---- PV: A=V^T (h x 32keys), B=P^T from the lane's own cvt_pk words ----
#pragma unroll
    for (int J = 0; J < 2; ++J) {
      union { unsigned int uu[4]; bf16x8 v; } pk;
      pk.uu[0] = cvw[2 * J][0];
      pk.uu[1] = cvw[2 * J][1];
      pk.uu[2] = cvw[2 * J + 1][0];
      pk.uu[3] = cvw[2 * J + 1][1];
#pragma unroll
      for (int hf = 0; hf < 4; ++hf)
        oacc[hf] = __builtin_amdgcn_mfma_f32_16x16x32_bf16(vf[hf][J], pk.v, oacc[hf], 0, 0, 0);
    }
  }

  // ---- write partials: po[u][q][h], ml[u][{m,l}][q] ----
  const size_t ug = (size_t)b * NUNIT + u;
  float* pop = po + (ug * 64 + w * 16 + l15) * 64;
#pragma unroll
  for (int hf = 0; hf < 4; ++hf)
    *(f32x4*)(pop + hf * 16 + l4 * 4) = oacc[hf];
  if (l4 == 0) {
    ml[ug * 128 + w * 16 + l15] = m;
    ml[ug * 128 + 64 + w * 16 + l15] = l;
  }
}

// ---------------- combine KV-split partials -> attnb (bf16) ----------
__global__ __launch_bounds__(256)
void combine_kernel(const float* __restrict__ po, const float* __restrict__ ml,
                    unsigned short* __restrict__ attnb)
{
  const int bid = blockIdx.x;          // 128 = B * 64 qtiles
  const int b = bid >> 6, qt = bid & 63;
  const int g = qt >> 2, r = qt & 3;
  const int nch = g + 1;
  const size_t ub = (size_t)b * NUNIT + (size_t)2 * g * (g + 1) + (size_t)r * (g + 1);
  const int tid = threadIdx.x;
  const int q = tid >> 2, hc = (tid & 3) * 16;

  float mt = -1e30f;
  for (int i = 0; i < nch; ++i) mt = fmaxf(mt, ml[(ub + i) * 128 + q]);
  float lt = 0.f;
  float4 a0 = {0,0,0,0}, a1 = {0,0,0,0}, a2 = {0,0,0,0}, a3 = {0,0,0,0};
  for (int i = 0; i < nch; ++i) {
    const float mi = ml[(ub + i) * 128 + q];
    const float wi = (mi > -1e29f) ? __builtin_amdgcn_exp2f(mi - mt) : 0.f;
    lt += wi * ml[(ub + i) * 128 + 64 + q];
    const float* pp = po + ((ub + i) * 64 + q) * 64 + hc;
    float4 f0 = *(const float4*)(pp + 0);
    float4 f1 = *(const float4*)(pp + 4);
    float4 f2 = *(const float4*)(pp + 8);
    float4 f3 = *(const float4*)(pp + 12);
    a0.x += wi * f0.x; a0.y += wi * f0.y; a0.z += wi * f0.z; a0.w += wi * f0.w;
    a1.x += wi * f1.x; a1.y += wi * f1.y; a1.z += wi * f1.z; a1.w += wi * f1.w;
    a2.x += wi * f2.x; a2.y += wi * f2.y; a2.z += wi * f2.z; a2.w += wi * f2.w;
    a3.x += wi * f3.x; a3.y += wi * f3.y; a3.z += wi * f3.z; a3.w += wi * f3.w;
  }
  const float inv = (lt > 0.f) ? 1.f / lt : 0.f;
  unsigned short* op = attnb + ((size_t)b * 4096 + qt * 64 + q) * 64 + hc;
  us4 o;
  o[0] = f2bf(a0.x * inv); o[1] = f2bf(a0.y * inv); o[2] = f2bf(a0.z * inv); o[3] = f2bf(a0.w * inv);
  *(us4*)(op + 0) = o;
  o[0] = f2bf(a1.x * inv); o[1] = f2bf(a1.y * inv); o[2] = f2bf(a1.z * inv); o[3] = f2bf(a1.w * inv);
  *(us4*)(op + 4) = o;
  o[0] = f2bf(a2.x * inv); o[1] = f2bf(a2.y * inv); o[2] = f2bf(a2.z * inv); o[3] = f2bf(a2.w * inv);
  *(us4*)(op + 8) = o;
  o[0] = f2bf(a3.x * inv); o[1] = f2bf(a3.y * inv); o[2] = f2bf(a3.z * inv); o[3] = f2bf(a3.w * inv);
  *(us4*)(op + 12) = o;
}

// ---------------- o_proj GEMM: out[bt][o] = attn[bt][:] . ow_eff[o][:] ----------
__global__ __launch_bounds__(256)
void oproj_kernel(const unsigned short* __restrict__ attnb,
                  const unsigned short* __restrict__ oweff,
                  float* __restrict__ out)
{
  __shared__ __attribute__((aligned(16))) unsigned short As[128][64];
  __shared__ __attribute__((aligned(16))) unsigned short Bs[128][64];
  const int bid = blockIdx.x;   // 512 = 64 x 8
  const int swz = (bid & 7) * 64 + (bid >> 3);
  const int mt = swz >> 3, nt = swz & 7;
  const int m0 = mt << 7, n0 = nt << 7;
  const int tid = threadIdx.x, wid = tid >> 6, lane = tid & 63;
  const int wm = (wid >> 1) << 6, wn = (wid & 1) << 6;
  const int l15 = lane & 15, l4 = lane >> 4;

#pragma unroll
  for (int i = 0; i < 4; ++i) {
    int ch = wid * 4 + i;
    int r = ch * 8 + (lane >> 3), c = (lane & 7) * 8;
    gll16(attnb + (size_t)(m0 + r) * 64 + c, &As[ch * 8][0]);
    gll16(oweff + (size_t)(n0 + r) * 64 + c, &Bs[ch * 8][0]);
  }
  __syncthreads();

  f32x4 acc[4][4];
#pragma unroll
  for (int m = 0; m < 4; ++m)
#pragma unroll
    for (int n = 0; n < 4; ++n) acc[m][n] = (f32x4){0.f, 0.f, 0.f, 0.f};
#pragma unroll
  for (int kk = 0; kk < 2; ++kk) {
    bf16x8 af[4], bfr[4];
#pragma unroll
    for (int m = 0; m < 4; ++m) af[m] = *(const bf16x8*)&As[wm + m * 16 + l15][kk * 32 + l4 * 8];
#pragma unroll
    for (int n = 0; n < 4; ++n) bfr[n] = *(const bf16x8*)&Bs[wn + n * 16 + l15][kk * 32 + l4 * 8];
#pragma unroll
    for (int m = 0; m < 4; ++m)
#pragma unroll
      for (int n = 0; n < 4; ++n)
        acc[m][n] = __builtin_amdgcn_mfma_f32_16x16x32_bf16(af[m], bfr[n], acc[m][n], 0, 0, 0);
  }
#pragma unroll
  for (int m = 0; m < 4; ++m)
#pragma unroll
    for (int n = 0; n < 4; ++n)
#pragma unroll
      for (int r = 0; r < 4; ++r)
        out[(size_t)(m0 + wm + m * 16 + l4 * 4 + r) * 1024 + n0 + wn + n * 16 + l15] = acc[m][n][r];
}

extern "C" void kernel_launch(void* const* d_in, const int* in_sizes, int n_in,
                              void* d_out, int out_size, void* d_ws, size_t ws_size,
                              hipStream_t stream) {
  const float* x      = (const float*)d_in[0];
  const float* cosb   = (const float*)d_in[1];
  const float* sinb   = (const float*)d_in[2];
  const float* qw     = (const float*)d_in[3];
  const float* kproto = (const float*)d_in[4];
  const float* vproto = (const float*)d_in[5];
  const float* qb     = (const float*)d_in[6];
  const float* kb     = (const float*)d_in[7];
  const float* vb     = (const float*)d_in[8];
  const float* ow     = (const float*)d_in[9];
  float* out = (float*)d_out;
  char* ws = (char*)d_ws;

  float* routing        = (float*)(ws + OFF_ROUTING);
  unsigned short* xbf   = (unsigned short*)(ws + OFF_XBF);
  unsigned short* bpk   = (unsigned short*)(ws + OFF_BPK);
  float* qkv            = (float*)(ws + OFF_QKV);
  unsigned short* qbf   = (unsigned short*)(ws + OFF_QBF);
  unsigned short* kbf   = (unsigned short*)(ws + OFF_KBF);
  unsigned short* vT    = (unsigned short*)(ws + OFF_VT);
  unsigned short* attnb = (unsigned short*)(ws + OFF_ATTNB);
  unsigned short* oweff = (unsigned short*)(ws + OFF_OWEFF);
  // attention partials alias dead regions: po over xbf+bpk (dead after proj),
  // ml over qkv (dead after rope)
  float* po             = (float*)(ws + OFF_XBF);
  float* ml             = (float*)(ws + OFF_QKV);

  prep_kernel<<<2048, 256, 0, stream>>>(x, qw, kproto, vproto, qb, kb, vb, ow,
                                        routing, xbf, bpk, oweff);
  proj_gemm_kernel<<<1536, 512, 0, stream>>>(bpk, xbf, routing, qkv);
  rope_kernel<<<BT / 32, 256, 0, stream>>>(qkv, cosb, sinb, qbf, kbf, vT);
  attn_kernel<<<Bn * NUNIT, 256, 0, stream>>>(qbf, kbf, vT, po, ml);
  combine_kernel<<<128, 256, 0, stream>>>(po, ml, attnb);
  oproj_kernel<<<512, 256, 0, stream>>>(attnb, oweff, out);
}